// Round 7
// baseline (459.908 us; speedup 1.0000x reference)
//
#include <hip/hip_runtime.h>
#include <math.h>

// RNN_197568496340: 6-layer ReLU RNN (T=1024,B=2048,IN=2,H=20) + FC(20->2) + log_softmax.
//
// R12 = R11 (426us PASSING) + ONE delta: pin the 20 weight quads into arch VGPRs with
// empty asm "+v" (ext_vector v4f32 operands), once before the hot loop and at each
// 6-step steady boundary. R11's profile: VGPR_Count=88, ~129 VALU insts/wave-step vs
// ~90 needed -> ~40 v_accvgpr_read/step from AGPR-parked weights (gfx950 unified RF).
// The "v" constraint class excludes AGPRs -> allocator must keep weights resident.
// R9/R10 proved the ring-schedule failure was independent of this pin (identical
// absmax with/without), so this is its first clean test, on a validated base.
//
// Everything else identical to R11: 2048 single-wave blocks, diagonal layer schedule,
// double-buffered 8-slot LDS, zero barriers, deferred log_softmax (logsm pass),
// steady/edge split, 6-step unroll, incremental cursors, waves_per_eu(2,2).

#define TT 1024
#define BB 2048
#define HH 20
#define LL 6
#define SLOTW 40
#define BUFW  (8 * SLOTW)       // 320 words/parity: slots 0=x,1..6=layer outs,7=zeros
#define NSTEPS (TT + LL)        // 1030 (even)

// ws layout (floats)
#define WS_WI   0               // padded Wih: [6][20][20] (layer0 = Wih0 zero-padded)
#define WS_BIAS 2400            // BiasTab: [61][2]  (role 60 = fcb)

typedef float f4 __attribute__((ext_vector_type(4)));

#define PINQ(v) asm volatile("" : "+v"(v))
#define PINALL  do { PINQ(whA0); PINQ(whA1); PINQ(whA2); PINQ(whA3); PINQ(whA4);   \
                     PINQ(whB0); PINQ(whB1); PINQ(whB2); PINQ(whB3); PINQ(whB4);   \
                     PINQ(wiA0); PINQ(wiA1); PINQ(wiA2); PINQ(wiA3); PINQ(wiA4);   \
                     PINQ(wiB0); PINQ(wiB1); PINQ(wiB2); PINQ(wiB3); PINQ(wiB4); } while (0)

struct SteadyT { static constexpr bool value = true;  };
struct EdgeT   { static constexpr bool value = false; };

__global__ void stage_ws(const float* __restrict__ Wih0,
                         const float* __restrict__ Wih,
                         const float* __restrict__ bih,
                         const float* __restrict__ bhh,
                         const float* __restrict__ fcb,
                         float* __restrict__ ws) {
    const int i = threadIdx.x + blockIdx.x * blockDim.x;
    if (i < 2400) {
        const int l = i / 400, r = i % 400, j = r / 20, k = r % 20;
        float v;
        if (l == 0) v = (k < 2) ? Wih0[j * 2 + k] : 0.f;
        else        v = Wih[(l - 1) * 400 + r];
        ws[WS_WI + i] = v;
    }
    if (i < 122) {
        const int role = i >> 1, c = i & 1;
        float v;
        if (role < 60) {
            const int l = role / 10, j = 2 * (role % 10) + c;
            v = bih[l * HH + j] + bhh[l * HH + j];
        } else {
            v = fcb[c];
        }
        ws[WS_BIAS + i] = v;
    }
}

__global__ void logsm(float* __restrict__ o) {
    const size_t n = (size_t)TT * BB;            // float2 elements
    float2* p = (float2*)o;
    for (size_t idx = (size_t)blockIdx.x * blockDim.x + threadIdx.x; idx < n;
         idx += (size_t)gridDim.x * blockDim.x) {
        float2 v = p[idx];
        const float mx  = fmaxf(v.x, v.y);
        const float lse = mx + __logf(__expf(v.x - mx) + __expf(v.y - mx));
        p[idx] = make_float2(v.x - lse, v.y - lse);
    }
}

__global__ __attribute__((amdgpu_flat_work_group_size(64, 64), amdgpu_waves_per_eu(2, 2)))
void rnn_fused(const float* __restrict__ x,      // [1024][2048][2]
               const float* __restrict__ Whh,    // [6][20][20]
               const float* __restrict__ fcw,    // [2][20]
               const float* __restrict__ ws,     // staged WI_pad + BiasTab
               float* __restrict__ out)          // [1024][2048][2] (raw logits here)
{
    __shared__ __align__(16) float As[2 * BUFW];   // 2560 B

    const int lane = threadIdx.x;
    // XCD swizzle: consecutive b on the same XCD -> L2 locality
    const int b = ((blockIdx.x & 7) << 8) | (blockIdx.x >> 3);

    const int  role = (lane < 60) ? lane : 60;
    const int  l    = role / 10;            // 0..6 (6 = head pseudo-layer)
    const int  j    = 2 * (role % 10);      // 0 for head
    const bool head = (role == 60);

    // ---- branch-free uniform weight init (pointers differ, code identical) ----
    const f4* pwh = (const f4*)(head ? Whh : (Whh + (l * HH + j) * HH));
    const f4* pwi = (const f4*)(head ? fcw : (ws + WS_WI + (l * HH + j) * HH));
    const float2  bt  = *(const float2*)(ws + WS_BIAS + 2 * role);

    f4 whA0 = pwh[0], whA1 = pwh[1], whA2 = pwh[2], whA3 = pwh[3], whA4 = pwh[4];
    f4 whB0 = pwh[5], whB1 = pwh[6], whB2 = pwh[7], whB3 = pwh[8], whB4 = pwh[9];
    f4 wiA0 = pwi[0], wiA1 = pwi[1], wiA2 = pwi[2], wiA3 = pwi[3], wiA4 = pwi[4];
    f4 wiB0 = pwi[5], wiB1 = pwi[6], wiB2 = pwi[7], wiB3 = pwi[8], wiB4 = pwi[9];

    // ---- LDS init: everything zero (h(-1)=0, zero-slot stays zero forever) ----
    for (int i = lane; i < 2 * BUFW; i += 64) As[i] = 0.f;

    // x staging: x[0] -> buf0 slot0; ring lanes 61..63 hold x[1..3]
    const float2* xp = (const float2*)x;
    float2 xh = make_float2(0.f, 0.f);
    if (lane == 61) *(float2*)&As[0] = xp[b];
    if (lane >= 61) xh = xp[(size_t)(lane - 60) * BB + b];

    // per-lane LDS word offsets (uniform formula, head included)
    const int ioff = l * SLOTW;             // input slot (head: slot 6 = h5)
    const int hoff = (l + 1) * SLOTW;       // recurrent slot (head: slot 7 = zeros)

    // incremental global cursors
    const int rdc = (lane >= 61) ? (lane - 61) : 0;                 // ring phase 0..2
    float2*       oph  = (float2*)out + b - (ptrdiff_t)LL * BB;     // head cursor, t=s-6
    const float2* xq   = xp + (size_t)(rdc + 4) * BB + b;           // prefetch target x[s+4]
    const float2* xend = xp + (size_t)(TT - 1) * BB + b;

    auto step = [&](int s, int ph, const float* rb, float* wb, auto sc) {
        constexpr bool STEADY = decltype(sc)::value;
        const f4* hp = (const f4*)(rb + hoff);
        const f4* ip = (const f4*)(rb + ioff);
        const f4 h0 = hp[0], h1 = hp[1], h2 = hp[2], h3 = hp[3], h4 = hp[4];
        const f4 i0 = ip[0], i1 = ip[1], i2 = ip[2], i3 = ip[3], i4 = ip[4];

        float ah0 = 0.f, ah1 = 0.f;
        float ai0 = bt.x, ai1 = bt.y;
        ah0 = fmaf(whA0.x, h0.x, ah0); ah0 = fmaf(whA0.y, h0.y, ah0);
        ah0 = fmaf(whA0.z, h0.z, ah0); ah0 = fmaf(whA0.w, h0.w, ah0);
        ah0 = fmaf(whA1.x, h1.x, ah0); ah0 = fmaf(whA1.y, h1.y, ah0);
        ah0 = fmaf(whA1.z, h1.z, ah0); ah0 = fmaf(whA1.w, h1.w, ah0);
        ah0 = fmaf(whA2.x, h2.x, ah0); ah0 = fmaf(whA2.y, h2.y, ah0);
        ah0 = fmaf(whA2.z, h2.z, ah0); ah0 = fmaf(whA2.w, h2.w, ah0);
        ah0 = fmaf(whA3.x, h3.x, ah0); ah0 = fmaf(whA3.y, h3.y, ah0);
        ah0 = fmaf(whA3.z, h3.z, ah0); ah0 = fmaf(whA3.w, h3.w, ah0);
        ah0 = fmaf(whA4.x, h4.x, ah0); ah0 = fmaf(whA4.y, h4.y, ah0);
        ah0 = fmaf(whA4.z, h4.z, ah0); ah0 = fmaf(whA4.w, h4.w, ah0);
        ah1 = fmaf(whB0.x, h0.x, ah1); ah1 = fmaf(whB0.y, h0.y, ah1);
        ah1 = fmaf(whB0.z, h0.z, ah1); ah1 = fmaf(whB0.w, h0.w, ah1);
        ah1 = fmaf(whB1.x, h1.x, ah1); ah1 = fmaf(whB1.y, h1.y, ah1);
        ah1 = fmaf(whB1.z, h1.z, ah1); ah1 = fmaf(whB1.w, h1.w, ah1);
        ah1 = fmaf(whB2.x, h2.x, ah1); ah1 = fmaf(whB2.y, h2.y, ah1);
        ah1 = fmaf(whB2.z, h2.z, ah1); ah1 = fmaf(whB2.w, h2.w, ah1);
        ah1 = fmaf(whB3.x, h3.x, ah1); ah1 = fmaf(whB3.y, h3.y, ah1);
        ah1 = fmaf(whB3.z, h3.z, ah1); ah1 = fmaf(whB3.w, h3.w, ah1);
        ah1 = fmaf(whB4.x, h4.x, ah1); ah1 = fmaf(whB4.y, h4.y, ah1);
        ah1 = fmaf(whB4.z, h4.z, ah1); ah1 = fmaf(whB4.w, h4.w, ah1);
        ai0 = fmaf(wiA0.x, i0.x, ai0); ai0 = fmaf(wiA0.y, i0.y, ai0);
        ai0 = fmaf(wiA0.z, i0.z, ai0); ai0 = fmaf(wiA0.w, i0.w, ai0);
        ai0 = fmaf(wiA1.x, i1.x, ai0); ai0 = fmaf(wiA1.y, i1.y, ai0);
        ai0 = fmaf(wiA1.z, i1.z, ai0); ai0 = fmaf(wiA1.w, i1.w, ai0);
        ai0 = fmaf(wiA2.x, i2.x, ai0); ai0 = fmaf(wiA2.y, i2.y, ai0);
        ai0 = fmaf(wiA2.z, i2.z, ai0); ai0 = fmaf(wiA2.w, i2.w, ai0);
        ai0 = fmaf(wiA3.x, i3.x, ai0); ai0 = fmaf(wiA3.y, i3.y, ai0);
        ai0 = fmaf(wiA3.z, i3.z, ai0); ai0 = fmaf(wiA3.w, i3.w, ai0);
        ai0 = fmaf(wiA4.x, i4.x, ai0); ai0 = fmaf(wiA4.y, i4.y, ai0);
        ai0 = fmaf(wiA4.z, i4.z, ai0); ai0 = fmaf(wiA4.w, i4.w, ai0);
        ai1 = fmaf(wiB0.x, i0.x, ai1); ai1 = fmaf(wiB0.y, i0.y, ai1);
        ai1 = fmaf(wiB0.z, i0.z, ai1); ai1 = fmaf(wiB0.w, i0.w, ai1);
        ai1 = fmaf(wiB1.x, i1.x, ai1); ai1 = fmaf(wiB1.y, i1.y, ai1);
        ai1 = fmaf(wiB1.z, i1.z, ai1); ai1 = fmaf(wiB1.w, i1.w, ai1);
        ai1 = fmaf(wiB2.x, i2.x, ai1); ai1 = fmaf(wiB2.y, i2.y, ai1);
        ai1 = fmaf(wiB2.z, i2.z, ai1); ai1 = fmaf(wiB2.w, i2.w, ai1);
        ai1 = fmaf(wiB3.x, i3.x, ai1); ai1 = fmaf(wiB3.y, i3.y, ai1);
        ai1 = fmaf(wiB3.z, i3.z, ai1); ai1 = fmaf(wiB3.w, i3.w, ai1);
        ai1 = fmaf(wiB4.x, i4.x, ai1); ai1 = fmaf(wiB4.y, i4.y, ai1);
        ai1 = fmaf(wiB4.z, i4.z, ai1); ai1 = fmaf(wiB4.w, i4.w, ai1);
        const float a0 = ah0 + ai0;
        const float a1 = ah1 + ai1;

        if (role < 60) {
            if (STEADY || (unsigned)(s - l) < TT) {                  // t in [0,1023]
                float2 r;
                r.x = fmaxf(a0, 0.f);
                r.y = fmaxf(a1, 0.f);
                *(float2*)(wb + hoff + j) = r;
            }
        } else if (lane == 60) {
            if (STEADY || s >= LL) *oph = make_float2(a0, a1);       // raw logits
            oph += BB;
        } else {
            // x ring: lane rdc publishes x[s+1] when ph==rdc, then prefetches x[s+4]
            if (rdc == ph) {
                if (STEADY || s + 1 < TT) *(float2*)wb = xh;
                if (STEADY)              xh = *xq;                   // s+4 <= 1023 here
                else if (xq <= xend)     xh = *xq;
                xq += 3 * (size_t)BB;
            }
        }
        __builtin_amdgcn_sched_barrier(0);   // scheduling fence only
    };

    float* const buf0 = As;
    float* const buf1 = As + BUFW;

    PINALL;

    // ---- edge pre: s = 0..5 (ph = s%3, buffers alternate from buf0->buf1) ----
    step(0, 0, buf0, buf1, EdgeT{}); step(1, 1, buf1, buf0, EdgeT{});
    step(2, 2, buf0, buf1, EdgeT{}); step(3, 0, buf1, buf0, EdgeT{});
    step(4, 1, buf0, buf1, EdgeT{}); step(5, 2, buf1, buf0, EdgeT{});

    // ---- steady: s in [6,1020), 169 x 6 steps, all guards folded, s unused ----
#pragma unroll 1
    for (int it = 0; it < 169; ++it) {
        PINALL;
        step(0, 0, buf0, buf1, SteadyT{}); step(0, 1, buf1, buf0, SteadyT{});
        step(0, 2, buf0, buf1, SteadyT{}); step(0, 0, buf1, buf0, SteadyT{});
        step(0, 1, buf0, buf1, SteadyT{}); step(0, 2, buf1, buf0, SteadyT{});
    }
    PINALL;

    // ---- edge post: s = 1020..1029 (1020%3 == 0) ----
    step(1020, 0, buf0, buf1, EdgeT{}); step(1021, 1, buf1, buf0, EdgeT{});
    step(1022, 2, buf0, buf1, EdgeT{}); step(1023, 0, buf1, buf0, EdgeT{});
    step(1024, 1, buf0, buf1, EdgeT{}); step(1025, 2, buf1, buf0, EdgeT{});
    step(1026, 0, buf0, buf1, EdgeT{}); step(1027, 1, buf1, buf0, EdgeT{});
    step(1028, 2, buf0, buf1, EdgeT{}); step(1029, 0, buf1, buf0, EdgeT{});
}

extern "C" void kernel_launch(void* const* d_in, const int* in_sizes, int n_in,
                              void* d_out, int out_size, void* d_ws, size_t ws_size,
                              hipStream_t stream) {
    const float* x    = (const float*)d_in[0];
    const float* Wih0 = (const float*)d_in[1];
    const float* Wih  = (const float*)d_in[2];
    const float* Whh  = (const float*)d_in[3];
    const float* bih  = (const float*)d_in[4];
    const float* bhh  = (const float*)d_in[5];
    const float* fcw  = (const float*)d_in[6];
    const float* fcb  = (const float*)d_in[7];
    float* out = (float*)d_out;
    float* ws  = (float*)d_ws;

    stage_ws<<<dim3(3), dim3(1024), 0, stream>>>(Wih0, Wih, bih, bhh, fcb, ws);
    rnn_fused<<<dim3(BB), dim3(64), 0, stream>>>(x, Whh, fcw, ws, out);
    logsm<<<dim3(2048), dim3(256), 0, stream>>>(out);
}

// Round 8
// 429.557 us; speedup vs baseline: 1.0707x; 1.0707x over previous
//
#include <hip/hip_runtime.h>
#include <math.h>

// RNN_197568496340: 6-layer ReLU RNN (T=1024,B=2048,IN=2,H=20) + FC(20->2) + log_softmax.
//
// R13 = R11 (426us PASSING) + lag-2 diagonal schedule to hide the LDS round-trip.
// R11 profile: 993 cyc/SIMD-step = 516 issue + 477 stall (both waves lockstep-stall on
// the write->read LDS turnaround; lag-1 means EVERY operand read depends on the
// immediately preceding write phase). R12's asm-pin attacked a mis-estimated
// instruction tax and regressed - abandoned.
//
// Lag-2: layer l computes t = m - 2l at micro m.
//  - input operand of micro m+1 (= h_{l-1}, written at micro m-1) is read at the TOP
//    of micro m into spare regs (jq) -> a full micro (~500cyc) of latency slack.
//  - recurrent operand (written end of micro m) is read at the END of micro m (rq);
//    its latency hides under the 40 input-side FMAs scheduled first in micro m+1.
//  - parity: micro m writes buf[m&1]; recurrent reads buf[(m-1)&1]; input reads
//    buf[m&1] (same as write target, read-before-write in program order - per-wave
//    in-order LDS, the R5/R11-proven property; single wave, no cross-wave hazards).
//  - x-ring: at micro m, phase lane publishes x(m+2) into buf[m&1].slot0 (consumed by
//    the jq issue at top of micro m+1 for micro m+2); 3-lane ring, 3-micro prefetch
//    slack. x(0)/x(1) pre-staged into bufA/bufB before the loop.
//  - head = pseudo-layer 6 (lag 12), reads slot6 (h5) / slot7 (zeros); raw logits,
//    logsm pass applies log_softmax (R11-validated).
//  - micros 0..1035; steady (all guards folded) m in [12,1013], 167 x 6-unroll;
//    edges 0..11 and 1014..1035 with folded-constant guards.

#define TT 1024
#define BB 2048
#define HH 20
#define LL 6
#define SLOTW 40
#define BUFW  (8 * SLOTW)       // 320 words/parity: slots 0=x,1..6=layer outs,7=zeros
#define XS 0

// ws layout (floats)
#define WS_WI   0               // padded Wih: [6][20][20] (layer0 = Wih0 zero-padded)
#define WS_BIAS 2400            // BiasTab: [61][2]  (role 60 = fcb)

typedef float f4 __attribute__((ext_vector_type(4)));

__global__ void stage_ws(const float* __restrict__ Wih0,
                         const float* __restrict__ Wih,
                         const float* __restrict__ bih,
                         const float* __restrict__ bhh,
                         const float* __restrict__ fcb,
                         float* __restrict__ ws) {
    const int i = threadIdx.x + blockIdx.x * blockDim.x;
    if (i < 2400) {
        const int l = i / 400, r = i % 400, j = r / 20, k = r % 20;
        float v;
        if (l == 0) v = (k < 2) ? Wih0[j * 2 + k] : 0.f;
        else        v = Wih[(l - 1) * 400 + r];
        ws[WS_WI + i] = v;
    }
    if (i < 122) {
        const int role = i >> 1, c = i & 1;
        float v;
        if (role < 60) {
            const int l = role / 10, j = 2 * (role % 10) + c;
            v = bih[l * HH + j] + bhh[l * HH + j];
        } else {
            v = fcb[c];
        }
        ws[WS_BIAS + i] = v;
    }
}

__global__ void logsm(float* __restrict__ o) {
    const size_t n = (size_t)TT * BB;            // float2 elements
    float2* p = (float2*)o;
    for (size_t idx = (size_t)blockIdx.x * blockDim.x + threadIdx.x; idx < n;
         idx += (size_t)gridDim.x * blockDim.x) {
        float2 v = p[idx];
        const float mx  = fmaxf(v.x, v.y);
        const float lse = mx + __logf(__expf(v.x - mx) + __expf(v.y - mx));
        p[idx] = make_float2(v.x - lse, v.y - lse);
    }
}

// ---- hot-loop macros ----

#define MAC4(acc, W, Q) do {                                       \
    acc = fmaf((W).x, (Q).x, acc); acc = fmaf((W).y, (Q).y, acc);  \
    acc = fmaf((W).z, (Q).z, acc); acc = fmaf((W).w, (Q).w, acc); } while (0)

// MICRO(m): [jq issue for m+1] [FMA: input chains first, recurrent after]
//           [writes] [rq issue for m+1] [sched fence]
#define MICRO(M_, C0,C1,C2,C3,C4, N0,N1,N2,N3,N4, ST_) do {                        \
    float* const wb_ = (((M_) & 1) ? bufB : bufA);                                 \
    const float* const rb_ = (((M_) & 1) ? bufA : bufB);                           \
    { const f4* jp_ = (const f4*)(rb_ + ioff);                                     \
      N0 = jp_[0]; N1 = jp_[1]; N2 = jp_[2]; N3 = jp_[3]; N4 = jp_[4]; }           \
    float ai0 = bt.x, ai1 = bt.y, ah0 = 0.f, ah1 = 0.f;                            \
    MAC4(ai0, wiA0, C0); MAC4(ai1, wiB0, C0);                                      \
    MAC4(ai0, wiA1, C1); MAC4(ai1, wiB1, C1);                                      \
    MAC4(ai0, wiA2, C2); MAC4(ai1, wiB2, C2);                                      \
    MAC4(ai0, wiA3, C3); MAC4(ai1, wiB3, C3);                                      \
    MAC4(ai0, wiA4, C4); MAC4(ai1, wiB4, C4);                                      \
    MAC4(ah0, whA0, rq0); MAC4(ah1, whB0, rq0);                                    \
    MAC4(ah0, whA1, rq1); MAC4(ah1, whB1, rq1);                                    \
    MAC4(ah0, whA2, rq2); MAC4(ah1, whB2, rq2);                                    \
    MAC4(ah0, whA3, rq3); MAC4(ah1, whB3, rq3);                                    \
    MAC4(ah0, whA4, rq4); MAC4(ah1, whB4, rq4);                                    \
    const float a0 = ah0 + ai0;                                                    \
    const float a1 = ah1 + ai1;                                                    \
    if (lane < 60) {                                                               \
        if ((ST_) || (unsigned)((M_) - lag2) < TT)                                 \
            *(float2*)(wb_ + hoff + j) = make_float2(fmaxf(a0, 0.f), fmaxf(a1, 0.f)); \
    } else if (lane == 60) {                                                       \
        if ((ST_) || (unsigned)((M_) - 12) < TT) *oph = make_float2(a0, a1);       \
        oph += BB;                                                                 \
    } else {                                                                       \
        if (rdc == ((M_) % 3)) {                                                   \
            if ((ST_) || (M_) + 2 < TT) *(float2*)(wb_ + XS) = xh;                 \
            if ((ST_)) xh = *xq; else if (xq <= xend) xh = *xq;                    \
            xq += 3 * (size_t)BB;                                                  \
        }                                                                          \
    }                                                                              \
    { const f4* hp_ = (const f4*)(wb_ + hoff);                                     \
      rq0 = hp_[0]; rq1 = hp_[1]; rq2 = hp_[2]; rq3 = hp_[3]; rq4 = hp_[4]; }      \
    __builtin_amdgcn_sched_barrier(0);                                             \
} while (0)

// pair: even micro uses iq (filled last micro), fills jq; odd micro swapped
#define MPAIR(M_, ST_)                                                             \
    MICRO((M_),     iq0,iq1,iq2,iq3,iq4, jq0,jq1,jq2,jq3,jq4, ST_);                \
    MICRO((M_) + 1, jq0,jq1,jq2,jq3,jq4, iq0,iq1,iq2,iq3,iq4, ST_)

__global__ __attribute__((amdgpu_flat_work_group_size(64, 64), amdgpu_waves_per_eu(2, 2)))
void rnn_fused(const float* __restrict__ x,      // [1024][2048][2]
               const float* __restrict__ Whh,    // [6][20][20]
               const float* __restrict__ fcw,    // [2][20]
               const float* __restrict__ ws,     // staged WI_pad + BiasTab
               float* __restrict__ out)          // [1024][2048][2] (raw logits here)
{
    __shared__ __align__(16) float As[2 * BUFW];   // 2560 B

    const int lane = threadIdx.x;
    // XCD swizzle: consecutive b on the same XCD -> L2 locality
    const int b = ((blockIdx.x & 7) << 8) | (blockIdx.x >> 3);

    const int  role = (lane < 60) ? lane : 60;
    const int  l    = role / 10;            // 0..6 (6 = head pseudo-layer)
    const int  j    = 2 * (role % 10);      // 0 for head
    const bool head = (role == 60);
    const int  lag2 = 2 * l;                // write-guard lag (head: 12, via branch)

    // ---- branch-free uniform weight init ----
    const f4* pwh = (const f4*)(head ? Whh : (Whh + (l * HH + j) * HH));
    const f4* pwi = (const f4*)(head ? fcw : (ws + WS_WI + (l * HH + j) * HH));
    const float2 bt = *(const float2*)(ws + WS_BIAS + 2 * role);

    f4 whA0 = pwh[0], whA1 = pwh[1], whA2 = pwh[2], whA3 = pwh[3], whA4 = pwh[4];
    f4 whB0 = pwh[5], whB1 = pwh[6], whB2 = pwh[7], whB3 = pwh[8], whB4 = pwh[9];
    f4 wiA0 = pwi[0], wiA1 = pwi[1], wiA2 = pwi[2], wiA3 = pwi[3], wiA4 = pwi[4];
    f4 wiB0 = pwi[5], wiB1 = pwi[6], wiB2 = pwi[7], wiB3 = pwi[8], wiB4 = pwi[9];

    // per-lane LDS word offsets (uniform formula, head included)
    const int ioff = l * SLOTW;             // input slot (head: slot 6 = h5)
    const int hoff = (l + 1) * SLOTW;       // recurrent slot (head: slot 7 = zeros)

    float* const bufA = As;
    float* const bufB = As + BUFW;

    // ---- LDS init: everything zero; pre-stage x(0)->bufA, x(1)->bufB ----
    for (int i = lane; i < 2 * BUFW; i += 64) As[i] = 0.f;
    const float2* xp = (const float2*)x;
    float2 xh = make_float2(0.f, 0.f);
    if (lane == 61) *(float2*)(bufA + XS) = xp[b];                  // x(0)
    if (lane == 62) *(float2*)(bufB + XS) = xp[(size_t)BB + b];     // x(1)
    if (lane >= 61) xh = xp[(size_t)(lane - 61 + 2) * BB + b];      // hold x(2..4)

    const int rdc = (lane >= 61) ? (lane - 61) : 0;                 // ring phase 0..2
    const float2* xq   = xp + (size_t)(rdc + 5) * BB + b;           // next prefetch
    const float2* xend = xp + (size_t)(TT - 1) * BB + b;
    float2* oph = (float2*)out + b - (ptrdiff_t)12 * BB;            // head t = m-12

    // ---- pipeline prime: ci_0 from I_0 = bufA; rq_0 from R_0 = bufB (zeros) ----
    f4 iq0, iq1, iq2, iq3, iq4, jq0, jq1, jq2, jq3, jq4;
    f4 rq0, rq1, rq2, rq3, rq4;
    { const f4* ip_ = (const f4*)(bufA + ioff);
      iq0 = ip_[0]; iq1 = ip_[1]; iq2 = ip_[2]; iq3 = ip_[3]; iq4 = ip_[4]; }
    { const f4* hp_ = (const f4*)(bufB + hoff);
      rq0 = hp_[0]; rq1 = hp_[1]; rq2 = hp_[2]; rq3 = hp_[3]; rq4 = hp_[4]; }

    // ---- edge pre: m = 0..11 ----
    MPAIR(0, 0);  MPAIR(2, 0);  MPAIR(4, 0);
    MPAIR(6, 0);  MPAIR(8, 0);  MPAIR(10, 0);

    // ---- steady: m = 12..1013, 167 x 6 micros, all guards folded ----
#pragma unroll 1
    for (int it = 0; it < 167; ++it) {
        MPAIR(12, 1); MPAIR(14, 1); MPAIR(16, 1);
    }

    // ---- edge post: m = 1014..1035 ----
    MPAIR(1014, 0); MPAIR(1016, 0); MPAIR(1018, 0); MPAIR(1020, 0);
    MPAIR(1022, 0); MPAIR(1024, 0); MPAIR(1026, 0); MPAIR(1028, 0);
    MPAIR(1030, 0); MPAIR(1032, 0); MPAIR(1034, 0);
}

extern "C" void kernel_launch(void* const* d_in, const int* in_sizes, int n_in,
                              void* d_out, int out_size, void* d_ws, size_t ws_size,
                              hipStream_t stream) {
    const float* x    = (const float*)d_in[0];
    const float* Wih0 = (const float*)d_in[1];
    const float* Wih  = (const float*)d_in[2];
    const float* Whh  = (const float*)d_in[3];
    const float* bih  = (const float*)d_in[4];
    const float* bhh  = (const float*)d_in[5];
    const float* fcw  = (const float*)d_in[6];
    const float* fcb  = (const float*)d_in[7];
    float* out = (float*)d_out;
    float* ws  = (float*)d_ws;

    stage_ws<<<dim3(3), dim3(1024), 0, stream>>>(Wih0, Wih, bih, bhh, fcb, ws);
    rnn_fused<<<dim3(BB), dim3(64), 0, stream>>>(x, Whh, fcw, ws, out);
    logsm<<<dim3(2048), dim3(256), 0, stream>>>(out);
}

// Round 12
// 420.049 us; speedup vs baseline: 1.0949x; 1.0226x over previous
//
#include <hip/hip_runtime.h>
#include <math.h>

// RNN_197568496340: 6-layer ReLU RNN (T=1024,B=2048,IN=2,H=20) + FC(20->2) + log_softmax.
//
// R17 = R13 (fp32, PASSING, 426us) with steady-loop fences changed from
// sched_barrier(0) to sched_barrier(0x77): ALU|VALU|SALU|VMEM may cross, DS blocked.
// R16 lesson (permanent): sched_barrier(0) was LOAD-BEARING - the compiler can prove
// each lane's own LDS read/write regions disjoint (hoff = ioff+40 > ioff+19) and
// reorders ds ops across micros, breaking the order-dependent cross-lane handoff
// (absmax 2.03). Masked barrier keeps DS program order (correctness) while letting
// the scheduler float micro m+1's input-side MACs (jq loaded a micro earlier) into
// micro m's recurrent-lgkm stall window (the ~417 idle cyc/SIMD-step R13 measured).
// R15 lesson (permanent): fp16/bf16/MFMA datapaths die numerically (error x1e6).

#define TT 1024
#define BB 2048
#define HH 20
#define LL 6
#define SLOTW 40
#define BUFW  (8 * SLOTW)       // 320 words/parity: slots 0=x,1..6=layer outs,7=zeros
#define XS 0

// ws layout (floats)
#define WS_WI   0               // padded Wih: [6][20][20] (layer0 = Wih0 zero-padded)
#define WS_BIAS 2400            // BiasTab: [61][2]  (role 60 = fcb)

typedef float f4 __attribute__((ext_vector_type(4)));

__global__ void stage_ws(const float* __restrict__ Wih0,
                         const float* __restrict__ Wih,
                         const float* __restrict__ bih,
                         const float* __restrict__ bhh,
                         const float* __restrict__ fcb,
                         float* __restrict__ ws) {
    const int i = threadIdx.x + blockIdx.x * blockDim.x;
    if (i < 2400) {
        const int l = i / 400, r = i % 400, j = r / 20, k = r % 20;
        float v;
        if (l == 0) v = (k < 2) ? Wih0[j * 2 + k] : 0.f;
        else        v = Wih[(l - 1) * 400 + r];
        ws[WS_WI + i] = v;
    }
    if (i < 122) {
        const int role = i >> 1, c = i & 1;
        float v;
        if (role < 60) {
            const int l = role / 10, j = 2 * (role % 10) + c;
            v = bih[l * HH + j] + bhh[l * HH + j];
        } else {
            v = fcb[c];
        }
        ws[WS_BIAS + i] = v;
    }
}

__global__ void logsm(float* __restrict__ o) {
    const size_t n = (size_t)TT * BB;            // float2 elements
    float2* p = (float2*)o;
    for (size_t idx = (size_t)blockIdx.x * blockDim.x + threadIdx.x; idx < n;
         idx += (size_t)gridDim.x * blockDim.x) {
        float2 v = p[idx];
        const float mx  = fmaxf(v.x, v.y);
        const float lse = mx + __logf(__expf(v.x - mx) + __expf(v.y - mx));
        p[idx] = make_float2(v.x - lse, v.y - lse);
    }
}

// ---- hot-loop macros ----

#define MAC4(acc, W, Q) do {                                       \
    acc = fmaf((W).x, (Q).x, acc); acc = fmaf((W).y, (Q).y, acc);  \
    acc = fmaf((W).z, (Q).z, acc); acc = fmaf((W).w, (Q).w, acc); } while (0)

// MICRO(m): [jq issue for m+1] [FMA: input chains first, recurrent after]
//           [writes] [rq issue for m+1] [fence: full(0) on edges, masked(0x77) steady]
#define MICRO(M_, C0,C1,C2,C3,C4, N0,N1,N2,N3,N4, ST_, FULLFEN_) do {              \
    float* const wb_ = (((M_) & 1) ? bufB : bufA);                                 \
    const float* const rb_ = (((M_) & 1) ? bufA : bufB);                           \
    { const f4* jp_ = (const f4*)(rb_ + ioff);                                     \
      N0 = jp_[0]; N1 = jp_[1]; N2 = jp_[2]; N3 = jp_[3]; N4 = jp_[4]; }           \
    float ai0 = bt.x, ai1 = bt.y, ah0 = 0.f, ah1 = 0.f;                            \
    MAC4(ai0, wiA0, C0); MAC4(ai1, wiB0, C0);                                      \
    MAC4(ai0, wiA1, C1); MAC4(ai1, wiB1, C1);                                      \
    MAC4(ai0, wiA2, C2); MAC4(ai1, wiB2, C2);                                      \
    MAC4(ai0, wiA3, C3); MAC4(ai1, wiB3, C3);                                      \
    MAC4(ai0, wiA4, C4); MAC4(ai1, wiB4, C4);                                      \
    MAC4(ah0, whA0, rq0); MAC4(ah1, whB0, rq0);                                    \
    MAC4(ah0, whA1, rq1); MAC4(ah1, whB1, rq1);                                    \
    MAC4(ah0, whA2, rq2); MAC4(ah1, whB2, rq2);                                    \
    MAC4(ah0, whA3, rq3); MAC4(ah1, whB3, rq3);                                    \
    MAC4(ah0, whA4, rq4); MAC4(ah1, whB4, rq4);                                    \
    const float a0 = ah0 + ai0;                                                    \
    const float a1 = ah1 + ai1;                                                    \
    if (lane < 60) {                                                               \
        if ((ST_) || (unsigned)((M_) - lag2) < TT)                                 \
            *(float2*)(wb_ + hoff + j) = make_float2(fmaxf(a0, 0.f), fmaxf(a1, 0.f)); \
    } else if (lane == 60) {                                                       \
        if ((ST_) || (unsigned)((M_) - 12) < TT) *oph = make_float2(a0, a1);       \
        oph += BB;                                                                 \
    } else {                                                                       \
        if (rdc == ((M_) % 3)) {                                                   \
            if ((ST_) || (M_) + 2 < TT) *(float2*)(wb_ + XS) = xh;                 \
            if ((ST_)) xh = *xq; else if (xq <= xend) xh = *xq;                    \
            xq += 3 * (size_t)BB;                                                  \
        }                                                                          \
    }                                                                              \
    { const f4* hp_ = (const f4*)(wb_ + hoff);                                     \
      rq0 = hp_[0]; rq1 = hp_[1]; rq2 = hp_[2]; rq3 = hp_[3]; rq4 = hp_[4]; }      \
    if (FULLFEN_) __builtin_amdgcn_sched_barrier(0);                               \
    else          __builtin_amdgcn_sched_barrier(0x77);  /* DS classes blocked */  \
} while (0)

// pair: even micro uses iq (filled last micro), fills jq; odd micro swapped
#define MPAIR(M_, ST_, FULLFEN_)                                                   \
    MICRO((M_),     iq0,iq1,iq2,iq3,iq4, jq0,jq1,jq2,jq3,jq4, ST_, FULLFEN_);      \
    MICRO((M_) + 1, jq0,jq1,jq2,jq3,jq4, iq0,iq1,iq2,iq3,iq4, ST_, FULLFEN_)

__global__ __attribute__((amdgpu_flat_work_group_size(64, 64), amdgpu_waves_per_eu(2, 2)))
void rnn_fused(const float* __restrict__ x,      // [1024][2048][2]
               const float* __restrict__ Whh,    // [6][20][20]
               const float* __restrict__ fcw,    // [2][20]
               const float* __restrict__ ws,     // staged WI_pad + BiasTab
               float* __restrict__ out)          // [1024][2048][2] (raw logits here)
{
    __shared__ __align__(16) float As[2 * BUFW];   // 2560 B

    const int lane = threadIdx.x;
    // XCD swizzle: consecutive b on the same XCD -> L2 locality
    const int b = ((blockIdx.x & 7) << 8) | (blockIdx.x >> 3);

    const int  role = (lane < 60) ? lane : 60;
    const int  l    = role / 10;            // 0..6 (6 = head pseudo-layer)
    const int  j    = 2 * (role % 10);      // 0 for head
    const bool head = (role == 60);
    const int  lag2 = 2 * l;                // write-guard lag

    // ---- branch-free uniform weight init ----
    const f4* pwh = (const f4*)(head ? Whh : (Whh + (l * HH + j) * HH));
    const f4* pwi = (const f4*)(head ? fcw : (ws + WS_WI + (l * HH + j) * HH));
    const float2 bt = *(const float2*)(ws + WS_BIAS + 2 * role);

    f4 whA0 = pwh[0], whA1 = pwh[1], whA2 = pwh[2], whA3 = pwh[3], whA4 = pwh[4];
    f4 whB0 = pwh[5], whB1 = pwh[6], whB2 = pwh[7], whB3 = pwh[8], whB4 = pwh[9];
    f4 wiA0 = pwi[0], wiA1 = pwi[1], wiA2 = pwi[2], wiA3 = pwi[3], wiA4 = pwi[4];
    f4 wiB0 = pwi[5], wiB1 = pwi[6], wiB2 = pwi[7], wiB3 = pwi[8], wiB4 = pwi[9];

    // per-lane LDS word offsets (uniform formula, head included)
    const int ioff = l * SLOTW;             // input slot (head: slot 6 = h5)
    const int hoff = (l + 1) * SLOTW;       // recurrent slot (head: slot 7 = zeros)

    float* const bufA = As;
    float* const bufB = As + BUFW;

    // ---- LDS init: everything zero; pre-stage x(0)->bufA, x(1)->bufB ----
    for (int i = lane; i < 2 * BUFW; i += 64) As[i] = 0.f;
    const float2* xp = (const float2*)x;
    float2 xh = make_float2(0.f, 0.f);
    if (lane == 61) *(float2*)(bufA + XS) = xp[b];                  // x(0)
    if (lane == 62) *(float2*)(bufB + XS) = xp[(size_t)BB + b];     // x(1)
    if (lane >= 61) xh = xp[(size_t)(lane - 61 + 2) * BB + b];      // hold x(2..4)

    const int rdc = (lane >= 61) ? (lane - 61) : 0;                 // ring phase 0..2
    const float2* xq   = xp + (size_t)(rdc + 5) * BB + b;           // next prefetch
    const float2* xend = xp + (size_t)(TT - 1) * BB + b;
    float2* oph = (float2*)out + b - (ptrdiff_t)12 * BB;            // head t = m-12

    // ---- pipeline prime: iq (input, micro 0) from bufA; rq (recurrent) from bufB ----
    f4 iq0, iq1, iq2, iq3, iq4, jq0, jq1, jq2, jq3, jq4;
    f4 rq0, rq1, rq2, rq3, rq4;
    { const f4* ip_ = (const f4*)(bufA + ioff);
      iq0 = ip_[0]; iq1 = ip_[1]; iq2 = ip_[2]; iq3 = ip_[3]; iq4 = ip_[4]; }
    { const f4* hp_ = (const f4*)(bufB + hoff);
      rq0 = hp_[0]; rq1 = hp_[1]; rq2 = hp_[2]; rq3 = hp_[3]; rq4 = hp_[4]; }

    // ---- edge pre: m = 0..11 (full fences) ----
    MPAIR(0, 0, 1);  MPAIR(2, 0, 1);  MPAIR(4, 0, 1);
    MPAIR(6, 0, 1);  MPAIR(8, 0, 1);  MPAIR(10, 0, 1);

    // ---- steady: m = 12..1013, 167 x 6 micros, masked fences (DS pinned, ALU free) ----
#pragma unroll 1
    for (int it = 0; it < 167; ++it) {
        MPAIR(12, 1, 0); MPAIR(14, 1, 0); MPAIR(16, 1, 0);
    }

    // ---- edge post: m = 1014..1035 (full fences) ----
    MPAIR(1014, 0, 1); MPAIR(1016, 0, 1); MPAIR(1018, 0, 1); MPAIR(1020, 0, 1);
    MPAIR(1022, 0, 1); MPAIR(1024, 0, 1); MPAIR(1026, 0, 1); MPAIR(1028, 0, 1);
    MPAIR(1030, 0, 1); MPAIR(1032, 0, 1); MPAIR(1034, 0, 1);
}

extern "C" void kernel_launch(void* const* d_in, const int* in_sizes, int n_in,
                              void* d_out, int out_size, void* d_ws, size_t ws_size,
                              hipStream_t stream) {
    const float* x    = (const float*)d_in[0];
    const float* Wih0 = (const float*)d_in[1];
    const float* Wih  = (const float*)d_in[2];
    const float* Whh  = (const float*)d_in[3];
    const float* bih  = (const float*)d_in[4];
    const float* bhh  = (const float*)d_in[5];
    const float* fcw  = (const float*)d_in[6];
    const float* fcb  = (const float*)d_in[7];
    float* out = (float*)d_out;
    float* ws  = (float*)d_ws;

    stage_ws<<<dim3(3), dim3(1024), 0, stream>>>(Wih0, Wih, bih, bhh, fcb, ws);
    rnn_fused<<<dim3(BB), dim3(64), 0, stream>>>(x, Whh, fcw, ws, out);
    logsm<<<dim3(2048), dim3(256), 0, stream>>>(out);
}